// Round 7
// baseline (180.680 us; speedup 1.0000x reference)
//
#include <hip/hip_runtime.h>
#include <hip/hip_bf16.h>
#include <hip/hip_cooperative_groups.h>

namespace cg = cooperative_groups;

// KAN layer: out[n,i] = sum_{g,d} splines[i,g,d] * relu(1 - |x[n,d] - grid[g]|)
// B=8192, D=192, G=192, O=16.
//
// x,grid in [0,1] => relu is identity. Piecewise-linear in x per d:
//   sum_g s*(1-|x-r_g|) = Cp(g*) - x*A(g*),  g* = floor(x*191)
// A = 2P - T, Cp = T - U + 2Q; P,Q inclusive prefix sums of s and s*grid
// over g. Table tab[d][g][i] packed as u32 {lo=bf16(A), hi=bf16(Cp)}
// (2.36 MB) in d_ws; main = one u32 L2-gather + ~4 VALU per (n,d,i).
//
// R6 lesson: per-dispatch graph-replay overhead ~5 us. So: ONE cooperative
// dispatch: phase1 = zero out + build tab; grid.sync(); phase2 = R4 main
// as a persistent 4-iteration loop. d-chunk = vb&7 is block-invariant ->
// XCD L2 pinning preserved (each XCD reads only its 0.3 MB slice).

#define Dn 192
#define Gn 192
#define On 16
#define Bn 8192

#define DSPLIT 8
#define DCHUNK (Dn / DSPLIT)        // 24
#define VBLOCKS ((Bn / 16) * DSPLIT) // 4096 virtual blocks
#define GRID_F 1024                  // real blocks (x4 persistent reps)

__device__ __forceinline__ unsigned short f2bf(float f) {
    union { float f; unsigned u; } v; v.f = f;
    unsigned r = v.u + 0x7FFF + ((v.u >> 16) & 1);   // RTN-even
    return (unsigned short)(r >> 16);
}

// ---------------- pre body: one wave per (d,i) ---------------------------
__device__ __forceinline__ void pre_body(int w, int lane,
                                         const float* __restrict__ sp,
                                         const float* __restrict__ grid,
                                         unsigned* __restrict__ tab) {
    int d = w >> 4;
    int i = w & 15;

    int g0 = lane * 3;  // 192 = 64 lanes * 3 g's each
    const float* s_base = sp + (size_t)i * Gn * Dn + d;   // splines[i,g,d]
    float s0 = s_base[(size_t)(g0 + 0) * Dn];
    float s1 = s_base[(size_t)(g0 + 1) * Dn];
    float s2 = s_base[(size_t)(g0 + 2) * Dn];
    float q0 = s0 * grid[g0 + 0];
    float q1 = s1 * grid[g0 + 1];
    float q2 = s2 * grid[g0 + 2];

    float lp1 = s0 + s1, lp2 = lp1 + s2;
    float lq1 = q0 + q1, lq2 = lq1 + q2;
    float sP = lp2, sQ = lq2;
    #pragma unroll
    for (int off = 1; off < 64; off <<= 1) {
        float pP = __shfl_up(sP, off);
        float pQ = __shfl_up(sQ, off);
        if (lane >= off) { sP += pP; sQ += pQ; }
    }
    float exP = sP - lp2, exQ = sQ - lq2;
    float T = __shfl(sP, 63);
    float U = __shfl(sQ, 63);

    float P[3] = { exP + s0, exP + lp1, exP + lp2 };
    float Q[3] = { exQ + q0, exQ + lq1, exQ + lq2 };

    #pragma unroll
    for (int k = 0; k < 3; ++k) {
        int g = g0 + k;
        float A  = 2.0f * P[k] - T;
        float Cp = T - U + 2.0f * Q[k];
        unsigned packed = (unsigned)f2bf(A) | ((unsigned)f2bf(Cp) << 16);
        tab[((size_t)d * Gn + g) * On + i] = packed;
    }
}

// ---------------- main body: one virtual block (R4 structure) ------------
__device__ __forceinline__ void main_body(unsigned vb, int t,
                                          const float* __restrict__ x,
                                          const unsigned* __restrict__ tab,
                                          float* __restrict__ out) {
    int i  = t & 15;
    int nn = t >> 4;
    int chunk = vb & 7;                 // d-chunk == XCD under round-robin
    int n = (vb >> 3) * 16 + nn;
    int d0 = chunk * DCHUNK;

    const float4* xr = (const float4*)(x + (size_t)n * Dn + d0);  // 6 float4
    const unsigned* tb = tab + (size_t)d0 * Gn * On + i;

    float acc = 0.0f;
    #pragma unroll
    for (int d4 = 0; d4 < DCHUNK / 4; ++d4) {   // 6 iterations
        float4 xv = xr[d4];
        float vx[4] = { xv.x, xv.y, xv.z, xv.w };
        #pragma unroll
        for (int k = 0; k < 4; ++k) {
            float v = vx[k];
            int g = (int)(v * 191.0f);
            g = (g < 0) ? 0 : (g > 191 ? 191 : g);
            unsigned e = tb[((d4 * 4 + k) * Gn + g) * On];
            union { unsigned u; float f; } A, C;
            A.u = e << 16;            // bf16 lo -> f32
            C.u = e & 0xFFFF0000u;    // bf16 hi -> f32
            acc += C.f;
            acc = fmaf(-v, A.f, acc); // acc += Cp - x*A
        }
    }
    atomicAdd(&out[(size_t)n * On + i], acc);
}

// ---------------- fused cooperative kernel -------------------------------
__global__ __launch_bounds__(256) void kan_fused(const float* __restrict__ x,
                                                 const float* __restrict__ sp,
                                                 const float* __restrict__ grid,
                                                 unsigned* __restrict__ tab,
                                                 float* __restrict__ out) {
    int gtid = blockIdx.x * 256 + threadIdx.x;
    if (gtid < Bn * On) out[gtid] = 0.0f;       // zero for phase-2 atomics

    int w = gtid >> 6;
    int lane = threadIdx.x & 63;
    if (w < Dn * On) pre_body(w, lane, sp, grid, tab);

    cg::this_grid().sync();                     // tab + zeroed out visible

    int t = threadIdx.x;
    #pragma unroll
    for (int rep = 0; rep < VBLOCKS / GRID_F; ++rep)   // 4 persistent reps
        main_body(blockIdx.x + rep * GRID_F, t, x, tab, out);
}

// ---------------- fallback kernels (two-dispatch, R4-proven) --------------
__global__ __launch_bounds__(256) void kan_pre(const float* __restrict__ sp,
                                               const float* __restrict__ grid,
                                               unsigned* __restrict__ tab,
                                               float* __restrict__ out) {
    int gtid = blockIdx.x * blockDim.x + threadIdx.x;
    if (gtid < Bn * On) out[gtid] = 0.0f;
    int w = gtid >> 6;
    int lane = threadIdx.x & 63;
    if (w < Dn * On) pre_body(w, lane, sp, grid, tab);
}

__global__ __launch_bounds__(256) void kan_main(const float* __restrict__ x,
                                                const unsigned* __restrict__ tab,
                                                float* __restrict__ out) {
    main_body(blockIdx.x, threadIdx.x, x, tab, out);
}

// ---------------- fallback (ws too small): direct computation ------------
__global__ __launch_bounds__(256) void kan_naive(const float* __restrict__ x,
                                                 const float* __restrict__ sp,
                                                 const float* __restrict__ grid,
                                                 float* __restrict__ out) {
    __shared__ float xs[Dn];
    __shared__ float gsh[Gn];
    __shared__ float red[4];
    int n = blockIdx.x;
    int t = threadIdx.x;
    if (t < Dn) { xs[t] = x[(size_t)n * Dn + t]; gsh[t] = grid[t]; }
    __syncthreads();
    float acc[On];
    #pragma unroll
    for (int i = 0; i < On; ++i) acc[i] = 0.0f;
    for (int idx = t; idx < Gn * Dn; idx += 256) {
        int g = idx / Dn;
        int d = idx - g * Dn;
        float b = fmaxf(0.0f, 1.0f - fabsf(xs[d] - gsh[g]));
        #pragma unroll
        for (int i = 0; i < On; ++i)
            acc[i] += sp[(size_t)i * Gn * Dn + idx] * b;
    }
    for (int i = 0; i < On; ++i) {
        float v = acc[i];
        #pragma unroll
        for (int off = 32; off > 0; off >>= 1) v += __shfl_down(v, off);
        if ((t & 63) == 0) red[t >> 6] = v;
        __syncthreads();
        if (t == 0) out[(size_t)n * On + i] = red[0] + red[1] + red[2] + red[3];
        __syncthreads();
    }
}

extern "C" void kernel_launch(void* const* d_in, const int* in_sizes, int n_in,
                              void* d_out, int out_size, void* d_ws, size_t ws_size,
                              hipStream_t stream) {
    const float* x    = (const float*)d_in[0];
    const float* sp   = (const float*)d_in[1];
    const float* grid = (const float*)d_in[2];
    float* out = (float*)d_out;

    const size_t TAB_BYTES = (size_t)Dn * Gn * On * sizeof(unsigned);  // 2.36 MB
    if (ws_size < TAB_BYTES) {
        kan_naive<<<Bn, 256, 0, stream>>>(x, sp, grid, out);
        return;
    }
    unsigned* tab = (unsigned*)d_ws;

    // one-time device-capability probe (host-side, capture-safe, no sync)
    static int s_coop = -1;
    if (s_coop < 0) {
        int dev = 0;
        (void)hipGetDevice(&dev);
        int v = 0;
        if (hipDeviceGetAttribute(&v, hipDeviceAttributeCooperativeLaunch, dev) != hipSuccess)
            v = 0;
        s_coop = v;
    }

    if (s_coop) {
        void* args[] = { (void*)&x, (void*)&sp, (void*)&grid, (void*)&tab, (void*)&out };
        hipError_t e = hipLaunchCooperativeKernel((void*)kan_fused, dim3(GRID_F),
                                                  dim3(256), args, 0, stream);
        if (e == hipSuccess) return;
    }
    // two-dispatch fallback (R4-proven path)
    kan_pre<<<GRID_F, 256, 0, stream>>>(sp, grid, tab, out);
    kan_main<<<VBLOCKS, 256, 0, stream>>>(x, tab, out);
}

// Round 8
// 28.741 us; speedup vs baseline: 6.2865x; 6.2865x over previous
//
#include <hip/hip_runtime.h>
#include <hip/hip_bf16.h>

// KAN layer: out[n,i] = sum_{g,d} splines[i,g,d] * relu(1 - |x[n,d] - grid[g]|)
// B=8192, D=192, G=192, O=16.
//
// x,grid in [0,1] => relu is identity. Piecewise-linear in x per d:
//   sum_g s*(1-|x-r_g|) = Cp(g*) - x*A(g*),  g* = floor(x*191)
// A = 2P - T, Cp = T - U + 2Q; P,Q inclusive prefix sums of s and s*grid
// over g. Table tab[d][g][i] packed as u32 {lo=bf16(A), hi=bf16(Cp)}
// (2.36 MB) in d_ws; main = one u32 L2-gather + ~4 VALU per (n,d,i).
//
// R7 lessons: grid.sync() costs ~150us on gfx950 -> two plain dispatches.
// R8 change (single variable vs R4): pre was latency-bound (3 scattered
// loads/lane, ILP=3). New pre: block = (i, 64-d third), coalesced 256B row
// staging into padded LDS, segmented scan over g, scattered packed stores.

#define Dn 192
#define Gn 192
#define On 16
#define Bn 8192

#define DSPLIT 8
#define DCHUNK (Dn / DSPLIT)    // 24

__device__ __forceinline__ unsigned short f2bf(float f) {
    union { float f; unsigned u; } v; v.f = f;
    unsigned r = v.u + 0x7FFF + ((v.u >> 16) & 1);   // RTN-even
    return (unsigned short)(r >> 16);
}

// ---------------- precompute: block = (i, d-third of 64) -----------------
// 48 blocks x 1024 threads. Stage splines[i, :, d0:d0+64] coalesced into
// LDS (padded), per-d segmented scan over g (16 segs x 12), emit packed
// {bf16 A, bf16 Cp} with fire-and-forget scattered stores. Zeroes out[].
__global__ __launch_bounds__(1024) void kan_pre(const float* __restrict__ sp,
                                                const float* __restrict__ grid,
                                                unsigned* __restrict__ tab,
                                                float* __restrict__ out) {
    __shared__ float S[Gn][65];        // +1 pad: 49.9 KB
    __shared__ float gsh[Gn];
    __shared__ float segP[16][64];
    __shared__ float segQ[16][64];

    int t = threadIdx.x;

    // zero the output for main's atomics (131072 f32 = 32768 float4)
    {
        int zi = blockIdx.x * 1024 + t;
        if (zi < Bn * On / 4)
            ((float4*)out)[zi] = make_float4(0.f, 0.f, 0.f, 0.f);
    }

    int i  = blockIdx.x / 3;           // 0..15
    int d3 = blockIdx.x % 3;           // 0..2
    int d0 = d3 * 64;

    if (t < Gn) gsh[t] = grid[t];

    // stage: 192 g-rows x 64 d-cols, 256 B coalesced per row-load
    const float* base = sp + (size_t)i * Gn * Dn + d0;   // splines[i, g, d0+col]
    int col = t & 63;
    int r0  = t >> 6;                  // 0..15
    #pragma unroll
    for (int j = 0; j < 12; ++j) {
        int g = r0 + 16 * j;
        S[g][col] = base[(size_t)g * Dn + col];
    }
    __syncthreads();

    // pass 1: per-(d, seg) partials; thread = (dl = t&63, seg = t>>6)
    int dl = col, seg = r0;            // 64 d x 16 segs of 12 g
    float sP = 0.f, sQ = 0.f;
    #pragma unroll
    for (int k = 0; k < 12; ++k) {
        int g = seg * 12 + k;
        float s = S[g][dl];
        sP += s;
        sQ += s * gsh[g];
    }
    segP[seg][dl] = sP;
    segQ[seg][dl] = sQ;
    __syncthreads();

    // exclusive carry + totals for this d
    float exP = 0.f, exQ = 0.f, T = 0.f, U = 0.f;
    #pragma unroll
    for (int s2 = 0; s2 < 16; ++s2) {
        float p = segP[s2][dl], q = segQ[s2][dl];
        if (s2 < seg) { exP += p; exQ += q; }
        T += p; U += q;
    }

    // pass 2: rescan with carry, emit packed entries (scattered 4B stores)
    unsigned* dst = tab + (size_t)(d0 + dl) * Gn * On + i;
    float P = exP, Q = exQ;
    #pragma unroll
    for (int k = 0; k < 12; ++k) {
        int g = seg * 12 + k;
        float s = S[g][dl];
        P += s;
        Q += s * gsh[g];
        float A  = 2.0f * P - T;
        float Cp = T - U + 2.0f * Q;
        dst[(size_t)g * On] = (unsigned)f2bf(A) | ((unsigned)f2bf(Cp) << 16);
    }
}

// ---------------- main: R4-exact. thread = (i, n), d-chunk = bid&7 -------
__global__ __launch_bounds__(256) void kan_main(const float* __restrict__ x,
                                                const unsigned* __restrict__ tab,
                                                float* __restrict__ out) {
    int t = threadIdx.x;
    int i  = t & 15;
    int nn = t >> 4;                        // 0..15
    unsigned bid = blockIdx.x;              // 4096 blocks
    int chunk = bid & 7;                    // d-chunk == XCD under round-robin
    int n = (bid >> 3) * 16 + nn;
    int d0 = chunk * DCHUNK;

    const float4* xr = (const float4*)(x + (size_t)n * Dn + d0);  // 6 float4
    const unsigned* tb = tab + (size_t)d0 * Gn * On + i;

    float acc = 0.0f;
    #pragma unroll
    for (int d4 = 0; d4 < DCHUNK / 4; ++d4) {   // 6 iterations
        float4 xv = xr[d4];
        float vx[4] = { xv.x, xv.y, xv.z, xv.w };
        #pragma unroll
        for (int k = 0; k < 4; ++k) {
            float v = vx[k];
            int g = (int)(v * 191.0f);
            g = (g < 0) ? 0 : (g > 191 ? 191 : g);
            unsigned e = tb[((d4 * 4 + k) * Gn + g) * On];
            union { unsigned u; float f; } A, C;
            A.u = e << 16;            // bf16 lo -> f32
            C.u = e & 0xFFFF0000u;    // bf16 hi -> f32
            acc += C.f;
            acc = fmaf(-v, A.f, acc); // acc += Cp - x*A
        }
    }
    atomicAdd(&out[(size_t)n * On + i], acc);
}

// ---------------- fallback (ws too small): direct computation ------------
__global__ __launch_bounds__(256) void kan_naive(const float* __restrict__ x,
                                                 const float* __restrict__ sp,
                                                 const float* __restrict__ grid,
                                                 float* __restrict__ out) {
    __shared__ float xs[Dn];
    __shared__ float gsh[Gn];
    __shared__ float red[4];
    int n = blockIdx.x;
    int t = threadIdx.x;
    if (t < Dn) { xs[t] = x[(size_t)n * Dn + t]; gsh[t] = grid[t]; }
    __syncthreads();
    float acc[On];
    #pragma unroll
    for (int i = 0; i < On; ++i) acc[i] = 0.0f;
    for (int idx = t; idx < Gn * Dn; idx += 256) {
        int g = idx / Dn;
        int d = idx - g * Dn;
        float b = fmaxf(0.0f, 1.0f - fabsf(xs[d] - gsh[g]));
        #pragma unroll
        for (int i = 0; i < On; ++i)
            acc[i] += sp[(size_t)i * Gn * Dn + idx] * b;
    }
    for (int i = 0; i < On; ++i) {
        float v = acc[i];
        #pragma unroll
        for (int off = 32; off > 0; off >>= 1) v += __shfl_down(v, off);
        if ((t & 63) == 0) red[t >> 6] = v;
        __syncthreads();
        if (t == 0) out[(size_t)n * On + i] = red[0] + red[1] + red[2] + red[3];
        __syncthreads();
    }
}

extern "C" void kernel_launch(void* const* d_in, const int* in_sizes, int n_in,
                              void* d_out, int out_size, void* d_ws, size_t ws_size,
                              hipStream_t stream) {
    const float* x    = (const float*)d_in[0];
    const float* sp   = (const float*)d_in[1];
    const float* grid = (const float*)d_in[2];
    float* out = (float*)d_out;

    const size_t TAB_BYTES = (size_t)Dn * Gn * On * sizeof(unsigned);  // 2.36 MB
    if (ws_size >= TAB_BYTES) {
        unsigned* tab = (unsigned*)d_ws;
        kan_pre<<<On * 3, 1024, 0, stream>>>(sp, grid, tab, out);          // 48 blocks
        kan_main<<<(Bn / 16) * DSPLIT, 256, 0, stream>>>(x, tab, out);     // 4096 blocks
    } else {
        kan_naive<<<Bn, 256, 0, stream>>>(x, sp, grid, out);
    }
}

// Round 9
// 23.390 us; speedup vs baseline: 7.7246x; 1.2288x over previous
//
#include <hip/hip_runtime.h>
#include <hip/hip_bf16.h>

// KAN layer: out[n,i] = sum_{g,d} splines[i,g,d] * relu(1 - |x[n,d] - grid[g]|)
// B=8192, D=192, G=192, O=16.
//
// x,grid in [0,1] => relu is identity. Piecewise-linear in x per d:
//   sum_g s*(1-|x-r_g|) = Cp(g*) - x*A(g*),  g* = floor(x*191)
// A = 2P - T, Cp = T - U + 2Q; P,Q inclusive prefix sums of s and s*grid
// over g. Table tab[d][g][i] packed as u32 {lo=bf16(A), hi=bf16(Cp)}
// (2.36 MB) in d_ws; main = one u32 L2-gather + ~4 VALU per (n,d,i).
//
// R8 lessons: staged pre loses to scattered pre (x2 clean tests) -> R4 pre.
// R9 change (single variable vs R4): main was latency*MLP-bound (VGPR=20
// => ~3 gathers in flight; 32w/CU*3*64B/300cy = 12.6 TB/s = observed).
// Batch gathers 12-deep with explicit arrays + split accumulators.

#define Dn 192
#define Gn 192
#define On 16
#define Bn 8192

#define DSPLIT 8
#define DCHUNK (Dn / DSPLIT)    // 24

__device__ __forceinline__ unsigned short f2bf(float f) {
    union { float f; unsigned u; } v; v.f = f;
    unsigned r = v.u + 0x7FFF + ((v.u >> 16) & 1);   // RTN-even
    return (unsigned short)(r >> 16);
}

// ---------------- precompute (R4-exact): one wave per (d,i) --------------
__global__ __launch_bounds__(256) void kan_pre(const float* __restrict__ sp,
                                               const float* __restrict__ grid,
                                               unsigned* __restrict__ tab,
                                               float* __restrict__ out) {
    int gtid = blockIdx.x * blockDim.x + threadIdx.x;
    if (gtid < Bn * On) out[gtid] = 0.0f;   // zero output for main's atomics

    int w = gtid >> 6;          // global wave id
    int lane = threadIdx.x & 63;
    if (w >= Dn * On) return;   // 3072 waves
    int d = w >> 4;
    int i = w & 15;

    int g0 = lane * 3;  // 192 = 64 lanes * 3 g's each
    const float* s_base = sp + (size_t)i * Gn * Dn + d;   // splines[i,g,d]
    float s0 = s_base[(size_t)(g0 + 0) * Dn];
    float s1 = s_base[(size_t)(g0 + 1) * Dn];
    float s2 = s_base[(size_t)(g0 + 2) * Dn];
    float q0 = s0 * grid[g0 + 0];
    float q1 = s1 * grid[g0 + 1];
    float q2 = s2 * grid[g0 + 2];

    float lp1 = s0 + s1, lp2 = lp1 + s2;
    float lq1 = q0 + q1, lq2 = lq1 + q2;
    float sP = lp2, sQ = lq2;
    #pragma unroll
    for (int off = 1; off < 64; off <<= 1) {
        float pP = __shfl_up(sP, off);
        float pQ = __shfl_up(sQ, off);
        if (lane >= off) { sP += pP; sQ += pQ; }
    }
    float exP = sP - lp2, exQ = sQ - lq2;
    float T = __shfl(sP, 63);
    float U = __shfl(sQ, 63);

    float P[3] = { exP + s0, exP + lp1, exP + lp2 };
    float Q[3] = { exQ + q0, exQ + lq1, exQ + lq2 };

    #pragma unroll
    for (int k = 0; k < 3; ++k) {
        int g = g0 + k;
        float A  = 2.0f * P[k] - T;
        float Cp = T - U + 2.0f * Q[k];
        unsigned packed = (unsigned)f2bf(A) | ((unsigned)f2bf(Cp) << 16);
        tab[((size_t)d * Gn + g) * On + i] = packed;
    }
}

// ---------------- main: thread = (i, n); 12-deep batched gathers ---------
__global__ __launch_bounds__(256) void kan_main(const float* __restrict__ x,
                                                const unsigned* __restrict__ tab,
                                                float* __restrict__ out) {
    int t = threadIdx.x;
    int i  = t & 15;
    int nn = t >> 4;                        // 0..15
    unsigned bid = blockIdx.x;              // 4096 blocks
    int chunk = bid & 7;                    // d-chunk == XCD under round-robin
    int n = (bid >> 3) * 16 + nn;
    int d0 = chunk * DCHUNK;

    const float4* xr = (const float4*)(x + (size_t)n * Dn + d0);  // 6 float4
    const unsigned* tb = tab + (size_t)d0 * Gn * On + i;

    float acc0 = 0.0f, acc1 = 0.0f;
    #pragma unroll
    for (int h = 0; h < 2; ++h) {           // two 12-deep batches
        float4 xa = xr[h * 3 + 0];
        float4 xb = xr[h * 3 + 1];
        float4 xc = xr[h * 3 + 2];
        float vx[12] = { xa.x, xa.y, xa.z, xa.w,
                         xb.x, xb.y, xb.z, xb.w,
                         xc.x, xc.y, xc.z, xc.w };
        unsigned e[12];
        #pragma unroll
        for (int k = 0; k < 12; ++k) {      // independent: 12 loads in flight
            float v = vx[k];
            int g = (int)(v * 191.0f);
            g = (g < 0) ? 0 : (g > 191 ? 191 : g);
            e[k] = tb[((h * 12 + k) * Gn + g) * On];
        }
        #pragma unroll
        for (int k = 0; k < 12; ++k) {
            union { unsigned u; float f; } A, C;
            A.u = e[k] << 16;               // bf16 lo -> f32
            C.u = e[k] & 0xFFFF0000u;       // bf16 hi -> f32
            if (k & 1) { acc1 += C.f; acc1 = fmaf(-vx[k], A.f, acc1); }
            else       { acc0 += C.f; acc0 = fmaf(-vx[k], A.f, acc0); }
        }
    }
    atomicAdd(&out[(size_t)n * On + i], acc0 + acc1);
}

// ---------------- fallback (ws too small): direct computation ------------
__global__ __launch_bounds__(256) void kan_naive(const float* __restrict__ x,
                                                 const float* __restrict__ sp,
                                                 const float* __restrict__ grid,
                                                 float* __restrict__ out) {
    __shared__ float xs[Dn];
    __shared__ float gsh[Gn];
    __shared__ float red[4];
    int n = blockIdx.x;
    int t = threadIdx.x;
    if (t < Dn) { xs[t] = x[(size_t)n * Dn + t]; gsh[t] = grid[t]; }
    __syncthreads();
    float acc[On];
    #pragma unroll
    for (int i = 0; i < On; ++i) acc[i] = 0.0f;
    for (int idx = t; idx < Gn * Dn; idx += 256) {
        int g = idx / Dn;
        int d = idx - g * Dn;
        float b = fmaxf(0.0f, 1.0f - fabsf(xs[d] - gsh[g]));
        #pragma unroll
        for (int i = 0; i < On; ++i)
            acc[i] += sp[(size_t)i * Gn * Dn + idx] * b;
    }
    for (int i = 0; i < On; ++i) {
        float v = acc[i];
        #pragma unroll
        for (int off = 32; off > 0; off >>= 1) v += __shfl_down(v, off);
        if ((t & 63) == 0) red[t >> 6] = v;
        __syncthreads();
        if (t == 0) out[(size_t)n * On + i] = red[0] + red[1] + red[2] + red[3];
        __syncthreads();
    }
}

extern "C" void kernel_launch(void* const* d_in, const int* in_sizes, int n_in,
                              void* d_out, int out_size, void* d_ws, size_t ws_size,
                              hipStream_t stream) {
    const float* x    = (const float*)d_in[0];
    const float* sp   = (const float*)d_in[1];
    const float* grid = (const float*)d_in[2];
    float* out = (float*)d_out;

    const size_t TAB_BYTES = (size_t)Dn * Gn * On * sizeof(unsigned);  // 2.36 MB
    if (ws_size >= TAB_BYTES) {
        unsigned* tab = (unsigned*)d_ws;
        kan_pre<<<(Dn * On * 64 + 255) / 256, 256, 0, stream>>>(sp, grid, tab, out);
        kan_main<<<(Bn / 16) * DSPLIT, 256, 0, stream>>>(x, tab, out);
    } else {
        kan_naive<<<Bn, 256, 0, stream>>>(x, sp, grid, out);
    }
}